// Round 6
// baseline (153.166 us; speedup 1.0000x reference)
//
#include <hip/hip_runtime.h>
#include <math.h>

#define NMESH 120
#define NKZ 61            // rfft half-spectrum along z
#define ALPHA_C 1.0

#define TILE 12           // mesh cells per tile per dim
#define NTPD 10           // tiles per dim
#define NTILE 1000
#define FP 17             // footprint per dim: TILE + 5
#define ZPAD 20           // z-padded inner row (16B-aligned rows)
#define FPSTRIDE 5792     // tile stride: 17*17*20=5780 -> 5792 (16B multiple)
#define CAP 256           // bucket capacity (Poisson(100): overflow ~1e-40)

#define CHUNK 128         // atoms staged per pass
// spread smem layout (floats): all rows stride-20, 16B aligned
#define WXA_OFF 0                     // [CHUNK][20] zero-padded wx
#define WYA_OFF (CHUNK*ZPAD)          // [CHUNK][20]
#define WZA_OFF (2*CHUNK*ZPAD)        // [CHUNK][20] (q folded into wz)
#define LYS_OFF (3*CHUNK*ZPAD)        // int[CHUNK]
#define SMEMF   (LYS_OFF + CHUNK)     // 7808 floats = 31232 B

#define YCH 12            // y-lines per fft_z block (1200 blocks)
#define XCH 4             // x per fft_y block / ky per fft_x block
#define YROW 137          // per-line Y storage: 8 rows * 17 + 1 pad (float2)

#define NSLOT 64          // accumulator slots (64B apart)
#define SLOTSTRIDE 8      // doubles per slot
#define W120C (-0.052359877559829887f)   // -2*pi/120

typedef float v2f __attribute__((ext_vector_type(2)));

// ---- workspace layout (bytes) ----
// [0, 12288)     : double ek/q/q2 slots (contiguous -> one memset)
// [115264, +23168000)  : float buf[1000][5792] tile footprints ([17][17][20])
// [23283264, +7027200) : float2 C1[x][kz][y]
//    counts + CAP-padded sorted atoms ALIAS the C1 region (dead before fft_z writes C1)
// C2[kz][ky][x] ALIASES buf (buf dead after fft_z)
#define EK_OFF      0
#define Q_OFF       4096
#define Q2_OFF      8192
#define BUF_OFF     115264
#define C1_OFF      23283264
#define C2_OFF      115264
#define COUNTS_OFF  C1_OFF
#define SORTED_OFF  (C1_OFF + 4096)

__device__ inline void inv3(const float* b, float* ib) {
    float a00=b[0],a01=b[1],a02=b[2],a10=b[3],a11=b[4],a12=b[5],a20=b[6],a21=b[7],a22=b[8];
    float c00 =  a11*a22 - a12*a21;
    float c01 = -(a10*a22 - a12*a20);
    float c02 =  a10*a21 - a11*a20;
    float c10 = -(a01*a22 - a02*a21);
    float c11 =  a00*a22 - a02*a20;
    float c12 = -(a00*a21 - a01*a20);
    float c20 =  a01*a12 - a02*a11;
    float c21 = -(a00*a12 - a02*a10);
    float c22 =  a00*a11 - a01*a10;
    float det = a00*c00 + a01*c01 + a02*c02;
    float inv = 1.0f/det;
    ib[0]=c00*inv; ib[1]=c10*inv; ib[2]=c20*inv;
    ib[3]=c01*inv; ib[4]=c11*inv; ib[5]=c21*inv;
    ib[6]=c02*inv; ib[7]=c12*inv; ib[8]=c22*inv;
}

__device__ inline void atom_pos(const float* __restrict__ box, float c0, float c1, float c2,
                                float* p) {
    float ib[9]; inv3(box, ib);
    #pragma unroll
    for (int d=0; d<3; ++d)
        p[d] = (c0*ib[0+d] + c1*ib[3+d] + c2*ib[6+d]) * 120.0f;
}

__device__ inline int wrap120(int i) { return ((i % 120) + 120) % 120; }

// order-6 Lagrange weights; x = pos - (floor(pos)+0.5)
__device__ inline void lag6(float x, float* w) {
    float df[6];
    #pragma unroll
    for (int k=0;k<6;++k) df[k] = x - ((float)k - 2.5f);
    w[0] = df[1]*df[2]*df[3]*df[4]*df[5] * (-1.0f/120.0f);
    w[1] = df[0]*df[2]*df[3]*df[4]*df[5] * ( 1.0f/24.0f);
    w[2] = df[0]*df[1]*df[3]*df[4]*df[5] * (-1.0f/12.0f);
    w[3] = df[0]*df[1]*df[2]*df[4]*df[5] * ( 1.0f/12.0f);
    w[4] = df[0]*df[1]*df[2]*df[3]*df[5] * (-1.0f/24.0f);
    w[5] = df[0]*df[1]*df[2]*df[3]*df[4] * ( 1.0f/120.0f);
}

// per-dim halo decomposition: cell c -> up to 2 (tile, local) pairs
__device__ inline int halo_pairs(int c, int* t, int* l) {
    int r = c % 12, ti = c / 12, n = 0;
    t[n] = ti;          l[n] = r + 2;  n++;
    if (r < 3)  { t[n] = (ti+9)%10; l[n] = r + 14; n++; }
    if (r >= 10){ t[n] = (ti+1)%10; l[n] = r - 10; n++; }
    return n;
}

// 8-point DFT, complex in (m-order), complex out (k-order). W8 = e^{-2pi i/8}.
__device__ inline void dft8(const float2* xin, float2* Y) {
    const float S = 0.70710678118654752f;
    float2 a=xin[0], b=xin[2], c=xin[4], d=xin[6];
    float s02r=a.x+c.x, s02i=a.y+c.y, d02r=a.x-c.x, d02i=a.y-c.y;
    float s13r=b.x+d.x, s13i=b.y+d.y, d13r=b.x-d.x, d13i=b.y-d.y;
    float2 E0 = make_float2(s02r+s13r, s02i+s13i);
    float2 E1 = make_float2(d02r+d13i, d02i-d13r);   // d02 - i*d13
    float2 E2 = make_float2(s02r-s13r, s02i-s13i);
    float2 E3 = make_float2(d02r-d13i, d02i+d13r);
    a=xin[1]; b=xin[3]; c=xin[5]; d=xin[7];
    s02r=a.x+c.x; s02i=a.y+c.y; d02r=a.x-c.x; d02i=a.y-c.y;
    s13r=b.x+d.x; s13i=b.y+d.y; d13r=b.x-d.x; d13i=b.y-d.y;
    float2 O0 = make_float2(s02r+s13r, s02i+s13i);
    float2 O1 = make_float2(d02r+d13i, d02i-d13r);
    float2 O2 = make_float2(s02r-s13r, s02i-s13i);
    float2 O3 = make_float2(d02r-d13i, d02i+d13r);
    float t1r = S*(O1.x + O1.y), t1i = S*(O1.y - O1.x);   // W8^1 * O1
    float t2r = O2.y,            t2i = -O2.x;             // W8^2 = -i
    float t3r = S*(O3.y - O3.x), t3i = -S*(O3.x + O3.y);  // W8^3
    Y[0] = make_float2(E0.x + O0.x, E0.y + O0.y);
    Y[4] = make_float2(E0.x - O0.x, E0.y - O0.y);
    Y[1] = make_float2(E1.x + t1r,  E1.y + t1i);
    Y[5] = make_float2(E1.x - t1r,  E1.y - t1i);
    Y[2] = make_float2(E2.x + t2r,  E2.y + t2i);
    Y[6] = make_float2(E2.x - t2r,  E2.y - t2i);
    Y[3] = make_float2(E3.x + t3r,  E3.y + t3i);
    Y[7] = make_float2(E3.x - t3r,  E3.y - t3i);
}

// one-pass bucket scatter + sum(q) + sum(q^2) into per-slot accumulators
__global__ void scatter_q_kernel(const float* __restrict__ coords,
                                 const float* __restrict__ box,
                                 const float* __restrict__ charges,
                                 int* __restrict__ counts,
                                 float4* __restrict__ sorted,
                                 double* __restrict__ qslots,
                                 double* __restrict__ q2slots, int n) {
    int i = blockIdx.x*blockDim.x + threadIdx.x;
    float v = 0.f, v2 = 0.f;
    if (i < n) {
        float p[3]; atom_pos(box, coords[3*i], coords[3*i+1], coords[3*i+2], p);
        float q = charges[i];
        v = q; v2 = q*q;
        int t[3];
        #pragma unroll
        for (int d=0; d<3; ++d) t[d] = wrap120((int)floorf(p[d])) / TILE;
        int tile = (t[0]*NTPD + t[1])*NTPD + t[2];
        int idx = atomicAdd(&counts[tile], 1);
        if (idx < CAP) sorted[tile*CAP + idx] = make_float4(p[0], p[1], p[2], q);
    }
    #pragma unroll
    for (int o=32;o>0;o>>=1) { v += __shfl_down(v,o,64); v2 += __shfl_down(v2,o,64); }
    __shared__ float s1[4], s2[4];
    int lane = threadIdx.x & 63, w = threadIdx.x >> 6;
    if (lane==0) { s1[w]=v; s2[w]=v2; }
    __syncthreads();
    if (threadIdx.x==0) {
        for (int j=1;j<4;j++) { v += s1[j]; v2 += s2[j]; }
        int slot = (blockIdx.x & (NSLOT-1)) * SLOTSTRIDE;
        atomicAdd(&qslots[slot],  (double)v);
        atomicAdd(&q2slots[slot], (double)v2);
    }
}

// Register-column spread, round-6 decomposition.
// Round-5 model (validated: 65 cyc/body x 260 wave-bodies/tile x 4 tiles/CU
// ~= measured 23.5 us): spread is LDS-read-THROUGHPUT bound -> the lever is
// fewer wave-bodies. Lane owns (A, B-quad): 85 owner lanes in TWO waves
// (was 289 owners in five waves). Wave0 (B0-15) takes every atom; wave1
// (B12-16) only atoms with ly>=7 (~42%). 142 wave-bodies/tile vs 260.
// acc = 17 z x 4 B = 34 v2f regs (packed-f32 FMA). Per-cell accumulation
// order unchanged -> bitwise-identical result vs round 5.
// Buf inner layout now [17][17][20] so the acc->LDS overlay writes are
// 16B-aligned ds_write_b128 (20 instrs/lane vs 68 scalar).
__global__ void __launch_bounds__(128, 4)
spread_tile_kernel(const float4* __restrict__ sorted,
                   const int* __restrict__ counts,
                   float* __restrict__ buf) {
    int tile = blockIdx.x;
    int tx = tile / (NTPD*NTPD);
    int rem = tile - tx*NTPD*NTPD;
    int ty = rem / NTPD;
    int tz = rem - ty*NTPD;
    int bx = tx*TILE, by = ty*TILE, bz = tz*TILE;

    __shared__ float smem[SMEMF];
    int* lys = (int*)&smem[LYS_OFF];

    int tid = threadIdx.x;
    int b = tid / 17;                  // B-quad index 0..7 (owners: 0..4)
    int A = tid - b*17;                // x-row 0..16
    int bc = (b > 4) ? 4 : b;          // clamp tail lanes to valid reads
    bool owner = (tid < 85);

    v2f acc[34];                       // [k][pair]: acc[2k]=(B4b,B4b+1), acc[2k+1]=(B4b+2,B4b+3)
    #pragma unroll
    for (int i=0;i<34;++i) acc[i] = (v2f){0.f, 0.f};

    int cntT = min(counts[tile], CAP);
    const float4* src = sorted + (size_t)tile*CAP;

    for (int start = 0; start < cntT; start += CHUNK) {
        int jn = cntT - start; if (jn > CHUNK) jn = CHUNK;
        __syncthreads();                 // prev-chunk readers done
        if (tid < jn) {
            float4 s = src[start + tid];
            float fx = floorf(s.x), fy = floorf(s.y), fz = floorf(s.z);
            float wx[6]; lag6(s.x - (fx + 0.5f), wx);
            float wy[6]; lag6(s.y - (fy + 0.5f), wy);
            float wz[6]; lag6(s.z - (fz + 0.5f), wz);
            int lx = wrap120((int)fx) - bx;
            int ly = wrap120((int)fy) - by;
            int lz = wrap120((int)fz) - bz;
            float4 z4 = make_float4(0.f,0.f,0.f,0.f);
            float4* px = (float4*)&smem[WXA_OFF + tid*ZPAD];
            float4* py = (float4*)&smem[WYA_OFF + tid*ZPAD];
            float4* pz = (float4*)&smem[WZA_OFF + tid*ZPAD];
            #pragma unroll
            for (int k=0;k<5;++k) { px[k]=z4; py[k]=z4; pz[k]=z4; }
            #pragma unroll
            for (int k=0;k<6;++k) {
                smem[WXA_OFF + tid*ZPAD + lx + k] = wx[k];
                smem[WYA_OFF + tid*ZPAD + ly + k] = wy[k];
                smem[WZA_OFF + tid*ZPAD + lz + k] = wz[k]*s.w;
            }
            lys[tid] = ly;
        }
        __syncthreads();
        auto body = [&](int j) {
            float wx_ = smem[WXA_OFF + j*ZPAD + A];
            float4 wy4 = *(const float4*)&smem[WYA_OFF + j*ZPAD + 4*bc];
            const float4* zp = (const float4*)&smem[WZA_OFF + j*ZPAD];
            float4 z0 = zp[0], z1 = zp[1], z2 = zp[2], z3 = zp[3];
            float z16 = smem[WZA_OFF + j*ZPAD + 16];
            v2f w2a = (v2f){wx_*wy4.x, wx_*wy4.y};
            v2f w2b = (v2f){wx_*wy4.z, wx_*wy4.w};
            float zv[17];
            zv[0]=z0.x;  zv[1]=z0.y;  zv[2]=z0.z;  zv[3]=z0.w;
            zv[4]=z1.x;  zv[5]=z1.y;  zv[6]=z1.z;  zv[7]=z1.w;
            zv[8]=z2.x;  zv[9]=z2.y;  zv[10]=z2.z; zv[11]=z2.w;
            zv[12]=z3.x; zv[13]=z3.y; zv[14]=z3.z; zv[15]=z3.w;
            zv[16]=z16;
            #pragma unroll
            for (int k=0;k<17;++k) {
                v2f zz = (v2f){zv[k], zv[k]};
                acc[2*k]   += w2a * zz;
                acc[2*k+1] += w2b * zz;
            }
        };
        if (tid < 64) {
            // wave0 covers B0-15: every atom's y-span (ly<=11) intersects
            #pragma unroll 2
            for (int j = 0; j < jn; ++j) body(j);
        } else {
            // wave1 covers B12-16: relevant iff ly+5 >= 12
            int lane = tid & 63;
            int l0 = lys[lane], l1 = lys[64 + lane];
            bool g0 = (lane < jn)      && (l0 >= 7);
            bool g1 = (64 + lane < jn) && (l1 >= 7);
            unsigned long long m0 = __ballot(g0);
            unsigned long long m1 = __ballot(g1);
            while (m0) { int j = __builtin_ctzll(m0); m0 &= m0-1ull; body(j); }
            while (m1) { int j = 64 + __builtin_ctzll(m1); m1 &= m1-1ull; body(j); }
        }
    }
    __syncthreads();
    // overlay: registers -> LDS footprint [(A*17+B)*20 + k], b128 runs
    if (owner) {
        #pragma unroll
        for (int db=0; db<4; ++db) {
            int Bv = 4*b + db;
            if (Bv <= 16) {
                float vals[17];
                #pragma unroll
                for (int k=0;k<17;++k)
                    vals[k] = (db & 1) ? acc[2*k + (db>>1)].y : acc[2*k + (db>>1)].x;
                float* dst = &smem[(A*17 + Bv)*ZPAD];
                *(float4*)&dst[0]  = make_float4(vals[0], vals[1], vals[2], vals[3]);
                *(float4*)&dst[4]  = make_float4(vals[4], vals[5], vals[6], vals[7]);
                *(float4*)&dst[8]  = make_float4(vals[8], vals[9], vals[10],vals[11]);
                *(float4*)&dst[12] = make_float4(vals[12],vals[13],vals[14],vals[15]);
                dst[16] = vals[16];
            }
        }
    }
    __syncthreads();
    float4* bp = (float4*)(buf + (size_t)tile * FPSTRIDE);
    const float4* sp = (const float4*)smem;
    for (int i = tid; i < FPSTRIDE/4; i += 128) bp[i] = sp[i];
}

// ---- radix-8 decimated 120-point DFT inner loop ----
// X[k] = sum_{j<15} Y[k&7][j] * W120^{k*j};  3 strands (j mod 3) for ILP.
// w1 twiddle from per-block LDS table (one sincos per k per block, not per output).
#define DFT15_BODY(Yp, kfreq, RE, IM)                                        \
    float w1r = tw[kfreq].x, w1i = tw[kfreq].y;                              \
    float w2r = w1r*w1r - w1i*w1i, w2i = 2.f*w1r*w1i;                        \
    float w3r = w2r*w1r - w2i*w1i, w3i = w2r*w1i + w2i*w1r;                  \
    float ar=1.f, ai=0.f, br=w1r, bi=w1i, cr=w2r, ci=w2i;                    \
    float r0_=0.f,i0_=0.f,r1_=0.f,i1_=0.f,r2_=0.f,i2_=0.f;                   \
    _Pragma("unroll")                                                        \
    for (int s_=0;s_<5;++s_) {                                               \
        float2 ya = (Yp)[3*s_], yb = (Yp)[3*s_+1], yc = (Yp)[3*s_+2];        \
        r0_ = fmaf(ya.x, ar, fmaf(-ya.y, ai, r0_));                          \
        i0_ = fmaf(ya.x, ai, fmaf( ya.y, ar, i0_));                          \
        r1_ = fmaf(yb.x, br, fmaf(-yb.y, bi, r1_));                          \
        i1_ = fmaf(yb.x, bi, fmaf( yb.y, br, i1_));                          \
        r2_ = fmaf(yc.x, cr, fmaf(-yc.y, ci, r2_));                          \
        i2_ = fmaf(yc.x, ci, fmaf( yc.y, cr, i2_));                          \
        float n_;                                                            \
        n_ = ar*w3r - ai*w3i; ai = ar*w3i + ai*w3r; ar = n_;                 \
        n_ = br*w3r - bi*w3i; bi = br*w3i + bi*w3r; br = n_;                 \
        n_ = cr*w3r - ci*w3i; ci = cr*w3i + ci*w3r; cr = n_;                 \
    }                                                                        \
    float RE = (r0_+r1_)+r2_, IM = (i0_+i1_)+i2_;

#define TWIDDLE_INIT()                                                       \
    __shared__ float2 tw[120];                                               \
    for (int k_ = threadIdx.x; k_ < 120; k_ += blockDim.x) {                 \
        float s_, c_; __sincosf(W120C * (float)k_, &s_, &c_);                \
        tw[k_] = make_float2(c_, s_);                                        \
    }

// stage 1: halo-gather + rfft along z (radix-8 pre-combine). out C1[x][kz][y].
__global__ void __launch_bounds__(256)
fft_z_kernel(const float* __restrict__ buf,
             float2* __restrict__ C1) {
    int x  = blockIdx.x / 10;
    int y0 = (blockIdx.x - x*10) * YCH;
    __shared__ float  lin[YCH][121];
    __shared__ float2 Ys[YCH][YROW];    // per line: 8 rows * 17 (+1 pad)
    TWIDDLE_INIT()

    int txA[2], lxA[2];
    int nx = halo_pairs(x, txA, lxA);

    for (int i = threadIdx.x; i < YCH*120; i += 256) {
        int yl = i / 120, z = i - yl*120;
        int tyA[2], lyA[2]; int ny = halo_pairs(y0 + yl, tyA, lyA);
        int tzA[2], lzA[2]; int nz = halo_pairs(z, tzA, lzA);
        float s = 0.f;
        for (int ii=0; ii<nx; ++ii)
            for (int jj=0; jj<ny; ++jj)
                for (int kk=0; kk<nz; ++kk) {
                    int tile = (txA[ii]*NTPD + tyA[jj])*NTPD + tzA[kk];
                    int cell = (lxA[ii]*FP + lyA[jj])*ZPAD + lzA[kk];
                    s += buf[(size_t)tile*FPSTRIDE + cell];
                }
        lin[yl][z] = s;
    }
    __syncthreads();
    // radix-8 combine: z = 15m + j ; Y[r][j] = sum_m x W8^{rm}
    for (int t = threadIdx.x; t < YCH*15; t += 256) {
        int yl = t / 15, j = t - (t/15)*15;
        float2 xin[8], Yo[8];
        #pragma unroll
        for (int m=0;m<8;++m) xin[m] = make_float2(lin[yl][15*m+j], 0.f);
        dft8(xin, Yo);
        #pragma unroll
        for (int r=0;r<8;++r) Ys[yl][r*17+j] = Yo[r];
    }
    __syncthreads();
    for (int o = threadIdx.x; o < YCH*NKZ; o += 256) {
        int kz = o / YCH, yl = o - (o/YCH)*YCH;
        const float2* Yp = &Ys[yl][(kz&7)*17];
        DFT15_BODY(Yp, kz, re, im)
        C1[(x*NKZ + kz)*120 + y0 + yl] = make_float2(re, im);
    }
}

// stage 2: cfft along y (radix-8). block = (4 consecutive x, kz). out C2[kz][ky][x].
__global__ void __launch_bounds__(256)
fft_y_kernel(const float2* __restrict__ C1,
             float2* __restrict__ C2) {
    int xc = blockIdx.x / NKZ;
    int kz = blockIdx.x - xc*NKZ;
    int x0 = xc * XCH;
    __shared__ float2 lin[XCH][121];
    __shared__ float2 Ys[XCH][YROW];
    TWIDDLE_INIT()
    for (int i = threadIdx.x; i < XCH*120; i += 256) {
        int xo = i / 120, y = i - (i/120)*120;
        lin[xo][y] = C1[((x0+xo)*NKZ + kz)*120 + y];
    }
    __syncthreads();
    for (int t = threadIdx.x; t < XCH*15; t += 256) {
        int xo = t / 15, j = t - (t/15)*15;
        float2 xin[8], Yo[8];
        #pragma unroll
        for (int m=0;m<8;++m) xin[m] = lin[xo][15*m+j];
        dft8(xin, Yo);
        #pragma unroll
        for (int r=0;r<8;++r) Ys[xo][r*17+j] = Yo[r];
    }
    __syncthreads();
    for (int o = threadIdx.x; o < XCH*120; o += 256) {
        int ky = o >> 2, xo = o & 3;
        const float2* Yp = &Ys[xo][(ky&7)*17];
        DFT15_BODY(Yp, ky, re, im)
        C2[(kz*120 + ky)*120 + x0 + xo] = make_float2(re, im);
    }
}

// stage 3: cfft along x (radix-8) + G-weighted energy (slotted atomic).
__global__ void __launch_bounds__(256)
fft_x_energy_kernel(const float2* __restrict__ C2,
                    const float* __restrict__ box,
                    double* __restrict__ ekslots) {
    int kyc = blockIdx.x / NKZ;
    int kz  = blockIdx.x - kyc*NKZ;
    int ky0 = kyc * XCH;
    __shared__ float2 lin[XCH][121];
    __shared__ float2 Ys[XCH][YROW];
    TWIDDLE_INIT()
    const float2* src = C2 + (kz*120 + ky0)*120;
    for (int i = threadIdx.x; i < XCH*120; i += 256) {
        int kyo = i / 120, xx = i - (i/120)*120;
        lin[kyo][xx] = src[i];
    }
    __syncthreads();
    for (int t = threadIdx.x; t < XCH*15; t += 256) {
        int kyo = t / 15, j = t - (t/15)*15;
        float2 xin[8], Yo[8];
        #pragma unroll
        for (int m=0;m<8;++m) xin[m] = lin[kyo][15*m+j];
        dft8(xin, Yo);
        #pragma unroll
        for (int r=0;r<8;++r) Ys[kyo][r*17+j] = Yo[r];
    }
    __syncthreads();
    float ib[9]; inv3(box, ib);
    const float TWOPI = 6.283185307179586f;
    float wzf = (kz==0 || kz==60) ? 1.0f : 2.0f;
    float contrib = 0.f;
    for (int o = threadIdx.x; o < XCH*120; o += 256) {
        int kyo = o / 120, kx = o - (o/120)*120;
        int ky = ky0 + kyo;
        const float2* Yp = &Ys[kyo][(kx&7)*17];
        DFT15_BODY(Yp, kx, re, im)
        if (!(kx==0 && ky==0 && kz==0)) {
            float mx = (kx < 60) ? (float)kx : (float)(kx - 120);
            float my = (ky < 60) ? (float)ky : (float)(ky - 120);
            float mz = (float)kz;
            float k0 = TWOPI*(mx*ib[0] + my*ib[1] + mz*ib[2]);
            float k1 = TWOPI*(mx*ib[3] + my*ib[4] + mz*ib[5]);
            float k2 = TWOPI*(mx*ib[6] + my*ib[7] + mz*ib[8]);
            float ksq = k0*k0 + k1*k1 + k2*k2;
            float G = 12.566370614359172f * __expf(-0.5f*(float)(ALPHA_C*ALPHA_C)*ksq) / ksq;
            contrib += wzf * G * (re*re + im*im);
        }
    }
    #pragma unroll
    for (int o=32;o>0;o>>=1) contrib += __shfl_down(contrib,o,64);
    __shared__ float sm[4];
    int lane = threadIdx.x & 63, w = threadIdx.x >> 6;
    if (lane==0) sm[w] = contrib;
    __syncthreads();
    if (threadIdx.x==0)
        atomicAdd(&ekslots[(blockIdx.x & (NSLOT-1)) * SLOTSTRIDE],
                  (double)(sm[0]+sm[1]+sm[2]+sm[3]));
}

// 64-lane slot reduction + closed-form corrections
__global__ void finalize_kernel(const double* __restrict__ ekslots,
                                const double* __restrict__ qslots,
                                const double* __restrict__ q2slots,
                                const float* __restrict__ box,
                                float* __restrict__ out) {
    int lane = threadIdx.x;
    double ek  = ekslots[lane*SLOTSTRIDE];
    double sq  = qslots [lane*SLOTSTRIDE];
    double sq2 = q2slots[lane*SLOTSTRIDE];
    #pragma unroll
    for (int o=32;o>0;o>>=1) {
        ek  += __shfl_down(ek,  o, 64);
        sq  += __shfl_down(sq,  o, 64);
        sq2 += __shfl_down(sq2, o, 64);
    }
    if (lane == 0) {
        double a00=box[0],a01=box[1],a02=box[2],a10=box[3],a11=box[4],a12=box[5],a20=box[6],a21=box[7],a22=box[8];
        double det = a00*(a11*a22-a12*a21) - a01*(a10*a22-a12*a20) + a02*(a10*a21-a11*a20);
        double vol = fabs(det);
        double E = ek/(2.0*vol)
                 - 0.5*sqrt(2.0/M_PI)/ALPHA_C * sq2
                 - M_PI*ALPHA_C*ALPHA_C * sq*sq / vol;
        out[0] = (float)E;
    }
}

extern "C" void kernel_launch(void* const* d_in, const int* in_sizes, int n_in,
                              void* d_out, int out_size, void* d_ws, size_t ws_size,
                              hipStream_t stream) {
    const float* coords  = (const float*)d_in[0];
    const float* box     = (const float*)d_in[1];
    const float* charges = (const float*)d_in[2];
    int n = in_sizes[0] / 3;

    char* ws = (char*)d_ws;
    double* ekslots = (double*)(ws + EK_OFF);
    double* qslots  = (double*)(ws + Q_OFF);
    double* q2slots = (double*)(ws + Q2_OFF);
    float*  buf     = (float*) (ws + BUF_OFF);
    float2* C1      = (float2*)(ws + C1_OFF);
    float2* C2      = (float2*)(ws + C2_OFF);
    int* counts     = (int*)(ws + COUNTS_OFF);
    float4* sorted  = (float4*)(ws + SORTED_OFF);

    int gA = (n + 255)/256;
    // init via memset nodes (replaces init_kernel: one fewer launch+gap)
    hipMemsetAsync(ws + EK_OFF, 0, 3*4096, stream);           // ek/q/q2 slots
    hipMemsetAsync(ws + COUNTS_OFF, 0, NTILE*sizeof(int), stream);
    scatter_q_kernel<<<gA, 256, 0, stream>>>(coords, box, charges, counts, sorted, qslots, q2slots, n);
    spread_tile_kernel<<<NTILE, 128, 0, stream>>>(sorted, counts, buf);
    fft_z_kernel<<<120*10, 256, 0, stream>>>(buf, C1);
    fft_y_kernel<<<30*NKZ, 256, 0, stream>>>(C1, C2);
    fft_x_energy_kernel<<<NKZ*30, 256, 0, stream>>>(C2, box, ekslots);
    finalize_kernel<<<1, 64, 0, stream>>>(ekslots, qslots, q2slots, box, (float*)d_out);
}

// Round 7
// 150.070 us; speedup vs baseline: 1.0206x; 1.0206x over previous
//
#include <hip/hip_runtime.h>
#include <math.h>

#define NMESH 120
#define NKZ 61            // rfft half-spectrum along z
#define ALPHA_C 1.0

#define TILE 12           // mesh cells per tile per dim
#define NTPD 10           // tiles per dim
#define NTILE 1000
#define FP 17             // footprint per dim: TILE + 5
#define ZPAD 20           // z-padded inner row (16B-aligned rows)
#define FPSTRIDE 5792     // tile stride: 17*17*20=5780 -> 5792 (16B multiple)
#define CAP 256           // bucket capacity (Poisson(100): overflow ~1e-40)

#define CHUNK 128         // atoms staged per pass
// spread smem layout (floats): wx/wy rows stride 17 (conflict-free scalar
// staging), wz rows stride 20 (16B-aligned b128 body reads)
#define WXA_OFF 0                     // [CHUNK][17]
#define WYA_OFF (CHUNK*17)            // [CHUNK][17]
#define WZA_OFF (2*CHUNK*17)          // [CHUNK][20]; byte off 17408, 16B-aligned
#define LYS_OFF (2*CHUNK*17 + CHUNK*20)  // int[CHUNK]
#define SMEMF   (LYS_OFF + CHUNK)     // 7040 floats = 28160 B (5 blocks/CU)

#define YCH 12            // y-lines per fft_z block (1200 blocks)
#define XCH 4             // x per fft_y block / ky per fft_x block
#define YROW 137          // per-line Y storage: 8 rows * 17 + 1 pad (float2)

#define NSLOT 64          // accumulator slots (64B apart)
#define SLOTSTRIDE 8      // doubles per slot
#define W120C (-0.052359877559829887f)   // -2*pi/120

typedef float v2f __attribute__((ext_vector_type(2)));

// ---- workspace layout (bytes) ----
// [0, 12288)     : double ek/q/q2 slots (one memset)
// [115264, +23168000)  : float buf[1000][5792] tile footprints ([17][17][20])
// [23283264, +7027200) : float2 C1[x][kz][y]
//    counts + CAP-padded sorted atoms ALIAS the C1 region (dead before fft_z writes C1)
// C2[kz][ky][x] ALIASES buf (buf dead after fft_z)
#define EK_OFF      0
#define Q_OFF       4096
#define Q2_OFF      8192
#define BUF_OFF     115264
#define C1_OFF      23283264
#define C2_OFF      115264
#define COUNTS_OFF  C1_OFF
#define SORTED_OFF  (C1_OFF + 4096)

__device__ inline void inv3(const float* b, float* ib) {
    float a00=b[0],a01=b[1],a02=b[2],a10=b[3],a11=b[4],a12=b[5],a20=b[6],a21=b[7],a22=b[8];
    float c00 =  a11*a22 - a12*a21;
    float c01 = -(a10*a22 - a12*a20);
    float c02 =  a10*a21 - a11*a20;
    float c10 = -(a01*a22 - a02*a21);
    float c11 =  a00*a22 - a02*a20;
    float c12 = -(a00*a21 - a01*a20);
    float c20 =  a01*a12 - a02*a11;
    float c21 = -(a00*a12 - a02*a10);
    float c22 =  a00*a11 - a01*a10;
    float det = a00*c00 + a01*c01 + a02*c02;
    float inv = 1.0f/det;
    ib[0]=c00*inv; ib[1]=c10*inv; ib[2]=c20*inv;
    ib[3]=c01*inv; ib[4]=c11*inv; ib[5]=c21*inv;
    ib[6]=c02*inv; ib[7]=c12*inv; ib[8]=c22*inv;
}

__device__ inline void atom_pos(const float* __restrict__ box, float c0, float c1, float c2,
                                float* p) {
    float ib[9]; inv3(box, ib);
    #pragma unroll
    for (int d=0; d<3; ++d)
        p[d] = (c0*ib[0+d] + c1*ib[3+d] + c2*ib[6+d]) * 120.0f;
}

__device__ inline int wrap120(int i) { return ((i % 120) + 120) % 120; }

// order-6 Lagrange weights; x = pos - (floor(pos)+0.5)
__device__ inline void lag6(float x, float* w) {
    float df[6];
    #pragma unroll
    for (int k=0;k<6;++k) df[k] = x - ((float)k - 2.5f);
    w[0] = df[1]*df[2]*df[3]*df[4]*df[5] * (-1.0f/120.0f);
    w[1] = df[0]*df[2]*df[3]*df[4]*df[5] * ( 1.0f/24.0f);
    w[2] = df[0]*df[1]*df[3]*df[4]*df[5] * (-1.0f/12.0f);
    w[3] = df[0]*df[1]*df[2]*df[4]*df[5] * ( 1.0f/12.0f);
    w[4] = df[0]*df[1]*df[2]*df[3]*df[5] * (-1.0f/24.0f);
    w[5] = df[0]*df[1]*df[2]*df[3]*df[4] * ( 1.0f/120.0f);
}

// per-dim halo decomposition: cell c -> up to 2 (tile, local) pairs
__device__ inline int halo_pairs(int c, int* t, int* l) {
    int r = c % 12, ti = c / 12, n = 0;
    t[n] = ti;          l[n] = r + 2;  n++;
    if (r < 3)  { t[n] = (ti+9)%10; l[n] = r + 14; n++; }
    if (r >= 10){ t[n] = (ti+1)%10; l[n] = r - 10; n++; }
    return n;
}

// 8-point DFT, complex in (m-order), complex out (k-order). W8 = e^{-2pi i/8}.
__device__ inline void dft8(const float2* xin, float2* Y) {
    const float S = 0.70710678118654752f;
    float2 a=xin[0], b=xin[2], c=xin[4], d=xin[6];
    float s02r=a.x+c.x, s02i=a.y+c.y, d02r=a.x-c.x, d02i=a.y-c.y;
    float s13r=b.x+d.x, s13i=b.y+d.y, d13r=b.x-d.x, d13i=b.y-d.y;
    float2 E0 = make_float2(s02r+s13r, s02i+s13i);
    float2 E1 = make_float2(d02r+d13i, d02i-d13r);   // d02 - i*d13
    float2 E2 = make_float2(s02r-s13r, s02i-s13i);
    float2 E3 = make_float2(d02r-d13i, d02i+d13r);
    a=xin[1]; b=xin[3]; c=xin[5]; d=xin[7];
    s02r=a.x+c.x; s02i=a.y+c.y; d02r=a.x-c.x; d02i=a.y-c.y;
    s13r=b.x+d.x; s13i=b.y+d.y; d13r=b.x-d.x; d13i=b.y-d.y;
    float2 O0 = make_float2(s02r+s13r, s02i+s13i);
    float2 O1 = make_float2(d02r+d13i, d02i-d13r);
    float2 O2 = make_float2(s02r-s13r, s02i-s13i);
    float2 O3 = make_float2(d02r-d13i, d02i+d13r);
    float t1r = S*(O1.x + O1.y), t1i = S*(O1.y - O1.x);   // W8^1 * O1
    float t2r = O2.y,            t2i = -O2.x;             // W8^2 = -i
    float t3r = S*(O3.y - O3.x), t3i = -S*(O3.x + O3.y);  // W8^3
    Y[0] = make_float2(E0.x + O0.x, E0.y + O0.y);
    Y[4] = make_float2(E0.x - O0.x, E0.y - O0.y);
    Y[1] = make_float2(E1.x + t1r,  E1.y + t1i);
    Y[5] = make_float2(E1.x - t1r,  E1.y - t1i);
    Y[2] = make_float2(E2.x + t2r,  E2.y + t2i);
    Y[6] = make_float2(E2.x - t2r,  E2.y - t2i);
    Y[3] = make_float2(E3.x + t3r,  E3.y + t3i);
    Y[7] = make_float2(E3.x - t3r,  E3.y - t3i);
}

// one-pass bucket scatter + sum(q) + sum(q^2) into per-slot accumulators
__global__ void scatter_q_kernel(const float* __restrict__ coords,
                                 const float* __restrict__ box,
                                 const float* __restrict__ charges,
                                 int* __restrict__ counts,
                                 float4* __restrict__ sorted,
                                 double* __restrict__ qslots,
                                 double* __restrict__ q2slots, int n) {
    int i = blockIdx.x*blockDim.x + threadIdx.x;
    float v = 0.f, v2 = 0.f;
    if (i < n) {
        float p[3]; atom_pos(box, coords[3*i], coords[3*i+1], coords[3*i+2], p);
        float q = charges[i];
        v = q; v2 = q*q;
        int t[3];
        #pragma unroll
        for (int d=0; d<3; ++d) t[d] = wrap120((int)floorf(p[d])) / TILE;
        int tile = (t[0]*NTPD + t[1])*NTPD + t[2];
        int idx = atomicAdd(&counts[tile], 1);
        if (idx < CAP) sorted[tile*CAP + idx] = make_float4(p[0], p[1], p[2], q);
    }
    #pragma unroll
    for (int o=32;o>0;o>>=1) { v += __shfl_down(v,o,64); v2 += __shfl_down(v2,o,64); }
    __shared__ float s1[4], s2[4];
    int lane = threadIdx.x & 63, w = threadIdx.x >> 6;
    if (lane==0) { s1[w]=v; s2[w]=v2; }
    __syncthreads();
    if (threadIdx.x==0) {
        for (int j=1;j<4;j++) { v += s1[j]; v2 += s2[j]; }
        int slot = (blockIdx.x & (NSLOT-1)) * SLOTSTRIDE;
        atomicAdd(&qslots[slot],  (double)v);
        atomicAdd(&q2slots[slot], (double)v2);
    }
}

// Register-column spread, round-7: B-range x atom-half decomposition.
// r6 lesson: grid is fixed at 1000 tiles -> cutting waves/block cut total
// waves (7.8/CU) and killed latency hiding. Here: 4 waves/block kept.
// waves {0,1} own B in [0,8] (3 triples), waves {2,3} own B in [9,16];
// within a pair, waves split the chunk's atoms half/half (balanced).
// Coverage = 0.75 + 0.67 = 1.42 wave-visits/atom (r5: ~2.6) at r5-level
// occupancy. Lane owns (A, B-triple): acc = 3 cols x 17 z = 51 f32
// (24 pk_fma + 3 fma per body). Half-partials combined with one
// deterministic LDS add pass (no atomics; per-cell f32 reorder proven
// safe by r1/r2 ds_add passes with absmax 0.0).
__global__ void __launch_bounds__(256, 4)
spread_tile_kernel(const float4* __restrict__ sorted,
                   const int* __restrict__ counts,
                   float* __restrict__ buf) {
    int tile = blockIdx.x;
    int tx = tile / (NTPD*NTPD);
    int rem = tile - tx*NTPD*NTPD;
    int ty = rem / NTPD;
    int tz = rem - ty*NTPD;
    int bx = tx*TILE, by = ty*TILE, bz = tz*TILE;

    __shared__ float smem[SMEMF];
    int* lys = (int*)&smem[LYS_OFF];

    int tid  = threadIdx.x;
    int wv   = tid >> 6;
    int lane = tid & 63;
    int half = wv & 1;                    // atom half: waves 0,2 -> [0,64); 1,3 -> [64,128)
    int blo  = (wv < 2) ? 0 : 9;          // B-range base
    int t3   = lane / 17; if (t3 > 2) t3 = 2;
    int A    = lane - 17*t3; if (A > 16) A = 16;
    bool owner = (lane < 51);
    int B0   = blo + 3*t3;
    bool c2ok = (B0 + 2 <= 16);           // third column valid (false only B0=15)

    v2f   acc2[3][8];
    float acc16[3];
    #pragma unroll
    for (int c=0;c<3;++c) {
        #pragma unroll
        for (int k=0;k<8;++k) acc2[c][k] = (v2f){0.f,0.f};
        acc16[c] = 0.f;
    }

    int cntT = min(counts[tile], CAP);
    const float4* src = sorted + (size_t)tile*CAP;

    for (int start = 0; start < cntT; start += CHUNK) {
        int jn = cntT - start; if (jn > CHUNK) jn = CHUNK;
        __syncthreads();                 // prev-chunk readers done
        if (tid < jn) {
            float4 s = src[start + tid];
            float fx = floorf(s.x), fy = floorf(s.y), fz = floorf(s.z);
            float wx[6]; lag6(s.x - (fx + 0.5f), wx);
            float wy[6]; lag6(s.y - (fy + 0.5f), wy);
            float wz[6]; lag6(s.z - (fz + 0.5f), wz);
            int lx = wrap120((int)fx) - bx;
            int ly = wrap120((int)fy) - by;
            int lz = wrap120((int)fz) - bz;
            #pragma unroll
            for (int k=0;k<17;++k) { smem[WXA_OFF + tid*17 + k] = 0.f;
                                     smem[WYA_OFF + tid*17 + k] = 0.f; }
            float4 z4 = make_float4(0.f,0.f,0.f,0.f);
            float4* pz = (float4*)&smem[WZA_OFF + tid*ZPAD];
            #pragma unroll
            for (int k=0;k<5;++k) pz[k] = z4;
            #pragma unroll
            for (int k=0;k<6;++k) {
                smem[WXA_OFF + tid*17 + lx + k] = wx[k];
                smem[WYA_OFF + tid*17 + ly + k] = wy[k];
                smem[WZA_OFF + tid*ZPAD + lz + k] = wz[k]*s.w;
            }
            lys[tid] = ly;
        }
        __syncthreads();
        int j0  = half * 64;
        int idx = j0 + lane;
        int lyv = lys[idx];                     // stale-safe (guarded below)
        bool g = (idx < jn) && (blo ? (lyv >= 4) : (lyv <= 8));
        unsigned long long m = __ballot(g);
        while (m) {
            int j = j0 + __builtin_ctzll(m); m &= m - 1ull;
            float wx_ = smem[WXA_OFF + j*17 + A];
            float wy0 = smem[WYA_OFF + j*17 + B0];
            float wy1 = smem[WYA_OFF + j*17 + B0 + 1];
            float wy2 = smem[WYA_OFF + j*17 + B0 + 2];   // in-smem even if B0+2==17
            float w2c[3];
            w2c[0] = wx_*wy0;
            w2c[1] = wx_*wy1;
            w2c[2] = c2ok ? wx_*wy2 : 0.f;
            const float4* zp = (const float4*)&smem[WZA_OFF + j*ZPAD];
            float4 z0 = zp[0], z1 = zp[1], z2 = zp[2], z3 = zp[3];
            float z16 = smem[WZA_OFF + j*ZPAD + 16];
            v2f zz[8];
            zz[0]=(v2f){z0.x,z0.y}; zz[1]=(v2f){z0.z,z0.w};
            zz[2]=(v2f){z1.x,z1.y}; zz[3]=(v2f){z1.z,z1.w};
            zz[4]=(v2f){z2.x,z2.y}; zz[5]=(v2f){z2.z,z2.w};
            zz[6]=(v2f){z3.x,z3.y}; zz[7]=(v2f){z3.z,z3.w};
            #pragma unroll
            for (int c=0;c<3;++c) {
                v2f wv2 = (v2f){w2c[c], w2c[c]};
                #pragma unroll
                for (int k=0;k<8;++k) acc2[c][k] += wv2 * zz[k];
                acc16[c] = fmaf(w2c[c], z16, acc16[c]);
            }
        }
    }
    __syncthreads();
    // overlay combine: waves 0,2 write their half-partials (disjoint B-sets),
    // then waves 1,3 add theirs (exclusive per-cell, deterministic).
    if ((half == 0) && owner) {
        #pragma unroll
        for (int c=0;c<3;++c) {
            int Bc = B0 + c;
            if (Bc <= 16) {
                float* dst = &smem[(A*17 + Bc)*ZPAD];
                *(float4*)&dst[0]  = make_float4(acc2[c][0].x, acc2[c][0].y, acc2[c][1].x, acc2[c][1].y);
                *(float4*)&dst[4]  = make_float4(acc2[c][2].x, acc2[c][2].y, acc2[c][3].x, acc2[c][3].y);
                *(float4*)&dst[8]  = make_float4(acc2[c][4].x, acc2[c][4].y, acc2[c][5].x, acc2[c][5].y);
                *(float4*)&dst[12] = make_float4(acc2[c][6].x, acc2[c][6].y, acc2[c][7].x, acc2[c][7].y);
                dst[16] = acc16[c];
            }
        }
    }
    __syncthreads();
    if ((half == 1) && owner) {
        #pragma unroll
        for (int c=0;c<3;++c) {
            int Bc = B0 + c;
            if (Bc <= 16) {
                float* dst = &smem[(A*17 + Bc)*ZPAD];
                float4 a0 = *(float4*)&dst[0],  a1 = *(float4*)&dst[4];
                float4 a2 = *(float4*)&dst[8],  a3 = *(float4*)&dst[12];
                float  a4 = dst[16];
                *(float4*)&dst[0]  = make_float4(a0.x+acc2[c][0].x, a0.y+acc2[c][0].y, a0.z+acc2[c][1].x, a0.w+acc2[c][1].y);
                *(float4*)&dst[4]  = make_float4(a1.x+acc2[c][2].x, a1.y+acc2[c][2].y, a1.z+acc2[c][3].x, a1.w+acc2[c][3].y);
                *(float4*)&dst[8]  = make_float4(a2.x+acc2[c][4].x, a2.y+acc2[c][4].y, a2.z+acc2[c][5].x, a2.w+acc2[c][5].y);
                *(float4*)&dst[12] = make_float4(a3.x+acc2[c][6].x, a3.y+acc2[c][6].y, a3.z+acc2[c][7].x, a3.w+acc2[c][7].y);
                dst[16] = a4 + acc16[c];
            }
        }
    }
    __syncthreads();
    float4* bp = (float4*)(buf + (size_t)tile * FPSTRIDE);
    const float4* sp = (const float4*)smem;
    for (int i = tid; i < FPSTRIDE/4; i += 256) bp[i] = sp[i];
}

// ---- radix-8 decimated 120-point DFT inner loop ----
// X[k] = sum_{j<15} Y[k&7][j] * W120^{k*j};  3 strands (j mod 3) for ILP.
// w1 twiddle from per-block LDS table (one sincos per k per block, not per output).
#define DFT15_BODY(Yp, kfreq, RE, IM)                                        \
    float w1r = tw[kfreq].x, w1i = tw[kfreq].y;                              \
    float w2r = w1r*w1r - w1i*w1i, w2i = 2.f*w1r*w1i;                        \
    float w3r = w2r*w1r - w2i*w1i, w3i = w2r*w1i + w2i*w1r;                  \
    float ar=1.f, ai=0.f, br=w1r, bi=w1i, cr=w2r, ci=w2i;                    \
    float r0_=0.f,i0_=0.f,r1_=0.f,i1_=0.f,r2_=0.f,i2_=0.f;                   \
    _Pragma("unroll")                                                        \
    for (int s_=0;s_<5;++s_) {                                               \
        float2 ya = (Yp)[3*s_], yb = (Yp)[3*s_+1], yc = (Yp)[3*s_+2];        \
        r0_ = fmaf(ya.x, ar, fmaf(-ya.y, ai, r0_));                          \
        i0_ = fmaf(ya.x, ai, fmaf( ya.y, ar, i0_));                          \
        r1_ = fmaf(yb.x, br, fmaf(-yb.y, bi, r1_));                          \
        i1_ = fmaf(yb.x, bi, fmaf( yb.y, br, i1_));                          \
        r2_ = fmaf(yc.x, cr, fmaf(-yc.y, ci, r2_));                          \
        i2_ = fmaf(yc.x, ci, fmaf( yc.y, cr, i2_));                          \
        float n_;                                                            \
        n_ = ar*w3r - ai*w3i; ai = ar*w3i + ai*w3r; ar = n_;                 \
        n_ = br*w3r - bi*w3i; bi = br*w3i + bi*w3r; br = n_;                 \
        n_ = cr*w3r - ci*w3i; ci = cr*w3i + ci*w3r; cr = n_;                 \
    }                                                                        \
    float RE = (r0_+r1_)+r2_, IM = (i0_+i1_)+i2_;

#define TWIDDLE_INIT()                                                       \
    __shared__ float2 tw[120];                                               \
    for (int k_ = threadIdx.x; k_ < 120; k_ += blockDim.x) {                 \
        float s_, c_; __sincosf(W120C * (float)k_, &s_, &c_);                \
        tw[k_] = make_float2(c_, s_);                                        \
    }

// stage 1: halo-gather + rfft along z (radix-8 pre-combine). out C1[x][kz][y].
__global__ void __launch_bounds__(256)
fft_z_kernel(const float* __restrict__ buf,
             float2* __restrict__ C1) {
    int x  = blockIdx.x / 10;
    int y0 = (blockIdx.x - x*10) * YCH;
    __shared__ float  lin[YCH][121];
    __shared__ float2 Ys[YCH][YROW];    // per line: 8 rows * 17 (+1 pad)
    TWIDDLE_INIT()

    int txA[2], lxA[2];
    int nx = halo_pairs(x, txA, lxA);

    for (int i = threadIdx.x; i < YCH*120; i += 256) {
        int yl = i / 120, z = i - yl*120;
        int tyA[2], lyA[2]; int ny = halo_pairs(y0 + yl, tyA, lyA);
        int tzA[2], lzA[2]; int nz = halo_pairs(z, tzA, lzA);
        float s = 0.f;
        for (int ii=0; ii<nx; ++ii)
            for (int jj=0; jj<ny; ++jj)
                for (int kk=0; kk<nz; ++kk) {
                    int tile = (txA[ii]*NTPD + tyA[jj])*NTPD + tzA[kk];
                    int cell = (lxA[ii]*FP + lyA[jj])*ZPAD + lzA[kk];
                    s += buf[(size_t)tile*FPSTRIDE + cell];
                }
        lin[yl][z] = s;
    }
    __syncthreads();
    // radix-8 combine: z = 15m + j ; Y[r][j] = sum_m x W8^{rm}
    for (int t = threadIdx.x; t < YCH*15; t += 256) {
        int yl = t / 15, j = t - (t/15)*15;
        float2 xin[8], Yo[8];
        #pragma unroll
        for (int m=0;m<8;++m) xin[m] = make_float2(lin[yl][15*m+j], 0.f);
        dft8(xin, Yo);
        #pragma unroll
        for (int r=0;r<8;++r) Ys[yl][r*17+j] = Yo[r];
    }
    __syncthreads();
    for (int o = threadIdx.x; o < YCH*NKZ; o += 256) {
        int kz = o / YCH, yl = o - (o/YCH)*YCH;
        const float2* Yp = &Ys[yl][(kz&7)*17];
        DFT15_BODY(Yp, kz, re, im)
        C1[(x*NKZ + kz)*120 + y0 + yl] = make_float2(re, im);
    }
}

// stage 2: cfft along y (radix-8). block = (4 consecutive x, kz). out C2[kz][ky][x].
__global__ void __launch_bounds__(256)
fft_y_kernel(const float2* __restrict__ C1,
             float2* __restrict__ C2) {
    int xc = blockIdx.x / NKZ;
    int kz = blockIdx.x - xc*NKZ;
    int x0 = xc * XCH;
    __shared__ float2 lin[XCH][121];
    __shared__ float2 Ys[XCH][YROW];
    TWIDDLE_INIT()
    for (int i = threadIdx.x; i < XCH*120; i += 256) {
        int xo = i / 120, y = i - (i/120)*120;
        lin[xo][y] = C1[((x0+xo)*NKZ + kz)*120 + y];
    }
    __syncthreads();
    for (int t = threadIdx.x; t < XCH*15; t += 256) {
        int xo = t / 15, j = t - (t/15)*15;
        float2 xin[8], Yo[8];
        #pragma unroll
        for (int m=0;m<8;++m) xin[m] = lin[xo][15*m+j];
        dft8(xin, Yo);
        #pragma unroll
        for (int r=0;r<8;++r) Ys[xo][r*17+j] = Yo[r];
    }
    __syncthreads();
    for (int o = threadIdx.x; o < XCH*120; o += 256) {
        int ky = o >> 2, xo = o & 3;
        const float2* Yp = &Ys[xo][(ky&7)*17];
        DFT15_BODY(Yp, ky, re, im)
        C2[(kz*120 + ky)*120 + x0 + xo] = make_float2(re, im);
    }
}

// stage 3: cfft along x (radix-8) + G-weighted energy (slotted atomic).
__global__ void __launch_bounds__(256)
fft_x_energy_kernel(const float2* __restrict__ C2,
                    const float* __restrict__ box,
                    double* __restrict__ ekslots) {
    int kyc = blockIdx.x / NKZ;
    int kz  = blockIdx.x - kyc*NKZ;
    int ky0 = kyc * XCH;
    __shared__ float2 lin[XCH][121];
    __shared__ float2 Ys[XCH][YROW];
    TWIDDLE_INIT()
    const float2* src = C2 + (kz*120 + ky0)*120;
    for (int i = threadIdx.x; i < XCH*120; i += 256) {
        int kyo = i / 120, xx = i - (i/120)*120;
        lin[kyo][xx] = src[i];
    }
    __syncthreads();
    for (int t = threadIdx.x; t < XCH*15; t += 256) {
        int kyo = t / 15, j = t - (t/15)*15;
        float2 xin[8], Yo[8];
        #pragma unroll
        for (int m=0;m<8;++m) xin[m] = lin[kyo][15*m+j];
        dft8(xin, Yo);
        #pragma unroll
        for (int r=0;r<8;++r) Ys[kyo][r*17+j] = Yo[r];
    }
    __syncthreads();
    float ib[9]; inv3(box, ib);
    const float TWOPI = 6.283185307179586f;
    float wzf = (kz==0 || kz==60) ? 1.0f : 2.0f;
    float contrib = 0.f;
    for (int o = threadIdx.x; o < XCH*120; o += 256) {
        int kyo = o / 120, kx = o - (o/120)*120;
        int ky = ky0 + kyo;
        const float2* Yp = &Ys[kyo][(kx&7)*17];
        DFT15_BODY(Yp, kx, re, im)
        if (!(kx==0 && ky==0 && kz==0)) {
            float mx = (kx < 60) ? (float)kx : (float)(kx - 120);
            float my = (ky < 60) ? (float)ky : (float)(ky - 120);
            float mz = (float)kz;
            float k0 = TWOPI*(mx*ib[0] + my*ib[1] + mz*ib[2]);
            float k1 = TWOPI*(mx*ib[3] + my*ib[4] + mz*ib[5]);
            float k2 = TWOPI*(mx*ib[6] + my*ib[7] + mz*ib[8]);
            float ksq = k0*k0 + k1*k1 + k2*k2;
            float G = 12.566370614359172f * __expf(-0.5f*(float)(ALPHA_C*ALPHA_C)*ksq) / ksq;
            contrib += wzf * G * (re*re + im*im);
        }
    }
    #pragma unroll
    for (int o=32;o>0;o>>=1) contrib += __shfl_down(contrib,o,64);
    __shared__ float sm[4];
    int lane = threadIdx.x & 63, w = threadIdx.x >> 6;
    if (lane==0) sm[w] = contrib;
    __syncthreads();
    if (threadIdx.x==0)
        atomicAdd(&ekslots[(blockIdx.x & (NSLOT-1)) * SLOTSTRIDE],
                  (double)(sm[0]+sm[1]+sm[2]+sm[3]));
}

// 64-lane slot reduction + closed-form corrections
__global__ void finalize_kernel(const double* __restrict__ ekslots,
                                const double* __restrict__ qslots,
                                const double* __restrict__ q2slots,
                                const float* __restrict__ box,
                                float* __restrict__ out) {
    int lane = threadIdx.x;
    double ek  = ekslots[lane*SLOTSTRIDE];
    double sq  = qslots [lane*SLOTSTRIDE];
    double sq2 = q2slots[lane*SLOTSTRIDE];
    #pragma unroll
    for (int o=32;o>0;o>>=1) {
        ek  += __shfl_down(ek,  o, 64);
        sq  += __shfl_down(sq,  o, 64);
        sq2 += __shfl_down(sq2, o, 64);
    }
    if (lane == 0) {
        double a00=box[0],a01=box[1],a02=box[2],a10=box[3],a11=box[4],a12=box[5],a20=box[6],a21=box[7],a22=box[8];
        double det = a00*(a11*a22-a12*a21) - a01*(a10*a22-a12*a20) + a02*(a10*a21-a11*a20);
        double vol = fabs(det);
        double E = ek/(2.0*vol)
                 - 0.5*sqrt(2.0/M_PI)/ALPHA_C * sq2
                 - M_PI*ALPHA_C*ALPHA_C * sq*sq / vol;
        out[0] = (float)E;
    }
}

extern "C" void kernel_launch(void* const* d_in, const int* in_sizes, int n_in,
                              void* d_out, int out_size, void* d_ws, size_t ws_size,
                              hipStream_t stream) {
    const float* coords  = (const float*)d_in[0];
    const float* box     = (const float*)d_in[1];
    const float* charges = (const float*)d_in[2];
    int n = in_sizes[0] / 3;

    char* ws = (char*)d_ws;
    double* ekslots = (double*)(ws + EK_OFF);
    double* qslots  = (double*)(ws + Q_OFF);
    double* q2slots = (double*)(ws + Q2_OFF);
    float*  buf     = (float*) (ws + BUF_OFF);
    float2* C1      = (float2*)(ws + C1_OFF);
    float2* C2      = (float2*)(ws + C2_OFF);
    int* counts     = (int*)(ws + COUNTS_OFF);
    float4* sorted  = (float4*)(ws + SORTED_OFF);

    int gA = (n + 255)/256;
    hipMemsetAsync(ws + EK_OFF, 0, 3*4096, stream);           // ek/q/q2 slots
    hipMemsetAsync(ws + COUNTS_OFF, 0, NTILE*sizeof(int), stream);
    scatter_q_kernel<<<gA, 256, 0, stream>>>(coords, box, charges, counts, sorted, qslots, q2slots, n);
    spread_tile_kernel<<<NTILE, 256, 0, stream>>>(sorted, counts, buf);
    fft_z_kernel<<<120*10, 256, 0, stream>>>(buf, C1);
    fft_y_kernel<<<30*NKZ, 256, 0, stream>>>(C1, C2);
    fft_x_energy_kernel<<<NKZ*30, 256, 0, stream>>>(C2, box, ekslots);
    finalize_kernel<<<1, 64, 0, stream>>>(ekslots, qslots, q2slots, box, (float*)d_out);
}

// Round 8
// 145.711 us; speedup vs baseline: 1.0512x; 1.0299x over previous
//
#include <hip/hip_runtime.h>
#include <math.h>

#define NMESH 120
#define NKZ 61            // rfft half-spectrum along z
#define ALPHA_C 1.0

#define TILE 12           // mesh cells per tile per dim
#define NTPD 10           // tiles per dim
#define NTILE 1000
#define FP 17             // footprint per dim: TILE + 5
#define ZPAD 20           // z-padded inner row (16B-aligned rows)
#define FPSTRIDE 5792     // tile stride: 17*17*20=5780 -> 5792 (16B multiple)
#define CAP 256           // bucket capacity (Poisson(100): overflow ~1e-40)

#define CHUNK 128         // atoms staged per pass
// spread smem layout (floats): ALL weight rows stride 20, 16B-aligned ->
// zeroing is 5x ds_write_b128 per array (was 34 scalar stores)
#define WXA_OFF 0                     // [CHUNK][20]
#define WYA_OFF (CHUNK*ZPAD)          // [CHUNK][20]
#define WZA_OFF (2*CHUNK*ZPAD)        // [CHUNK][20]
#define LYS_OFF (3*CHUNK*ZPAD)        // int[CHUNK]
#define SMEMF   (LYS_OFF + CHUNK)     // 7808 floats = 31232 B (5 blocks/CU)

#define YCH 12            // y-lines per fft_z block (1200 blocks)
#define XCH 4             // x per fft_y block / ky per fft_x block
#define YROW 137          // per-line Y storage: 8 rows * 17 + 1 pad (float2)

#define NSLOT 64          // accumulator slots (64B apart)
#define SLOTSTRIDE 8      // doubles per slot
#define W120C (-0.052359877559829887f)   // -2*pi/120

typedef float v2f __attribute__((ext_vector_type(2)));

// ---- workspace layout (bytes) ----
// [0, 12288)     : double ek/q/q2 slots
// [12288, 16384) : int counts[1000]           <- ONE memset covers [0,16384)
// [115264, +23168000)  : float buf[1000][5792] tile footprints ([17][17][20])
// [23283264, +7027200) : float2 C1[x][kz][y]
//    CAP-padded sorted atoms ALIAS the C1 region (dead before fft_z writes C1)
// C2[kz][ky][x] ALIASES buf (buf dead after fft_z)
#define EK_OFF      0
#define Q_OFF       4096
#define Q2_OFF      8192
#define COUNTS_OFF  12288
#define BUF_OFF     115264
#define C1_OFF      23283264
#define C2_OFF      115264
#define SORTED_OFF  (C1_OFF + 4096)

__device__ inline void inv3(const float* b, float* ib) {
    float a00=b[0],a01=b[1],a02=b[2],a10=b[3],a11=b[4],a12=b[5],a20=b[6],a21=b[7],a22=b[8];
    float c00 =  a11*a22 - a12*a21;
    float c01 = -(a10*a22 - a12*a20);
    float c02 =  a10*a21 - a11*a20;
    float c10 = -(a01*a22 - a02*a21);
    float c11 =  a00*a22 - a02*a20;
    float c12 = -(a00*a21 - a01*a20);
    float c20 =  a01*a12 - a02*a11;
    float c21 = -(a00*a12 - a02*a10);
    float c22 =  a00*a11 - a01*a10;
    float det = a00*c00 + a01*c01 + a02*c02;
    float inv = 1.0f/det;
    ib[0]=c00*inv; ib[1]=c10*inv; ib[2]=c20*inv;
    ib[3]=c01*inv; ib[4]=c11*inv; ib[5]=c21*inv;
    ib[6]=c02*inv; ib[7]=c12*inv; ib[8]=c22*inv;
}

__device__ inline void atom_pos(const float* __restrict__ box, float c0, float c1, float c2,
                                float* p) {
    float ib[9]; inv3(box, ib);
    #pragma unroll
    for (int d=0; d<3; ++d)
        p[d] = (c0*ib[0+d] + c1*ib[3+d] + c2*ib[6+d]) * 120.0f;
}

__device__ inline int wrap120(int i) { return ((i % 120) + 120) % 120; }

// order-6 Lagrange weights; x = pos - (floor(pos)+0.5)
__device__ inline void lag6(float x, float* w) {
    float df[6];
    #pragma unroll
    for (int k=0;k<6;++k) df[k] = x - ((float)k - 2.5f);
    w[0] = df[1]*df[2]*df[3]*df[4]*df[5] * (-1.0f/120.0f);
    w[1] = df[0]*df[2]*df[3]*df[4]*df[5] * ( 1.0f/24.0f);
    w[2] = df[0]*df[1]*df[3]*df[4]*df[5] * (-1.0f/12.0f);
    w[3] = df[0]*df[1]*df[2]*df[4]*df[5] * ( 1.0f/12.0f);
    w[4] = df[0]*df[1]*df[2]*df[3]*df[5] * (-1.0f/24.0f);
    w[5] = df[0]*df[1]*df[2]*df[3]*df[4] * ( 1.0f/120.0f);
}

// per-dim halo decomposition: cell c -> up to 2 (tile, local) pairs
__device__ inline int halo_pairs(int c, int* t, int* l) {
    int r = c % 12, ti = c / 12, n = 0;
    t[n] = ti;          l[n] = r + 2;  n++;
    if (r < 3)  { t[n] = (ti+9)%10; l[n] = r + 14; n++; }
    if (r >= 10){ t[n] = (ti+1)%10; l[n] = r - 10; n++; }
    return n;
}

// 8-point DFT, complex in (m-order), complex out (k-order). W8 = e^{-2pi i/8}.
__device__ inline void dft8(const float2* xin, float2* Y) {
    const float S = 0.70710678118654752f;
    float2 a=xin[0], b=xin[2], c=xin[4], d=xin[6];
    float s02r=a.x+c.x, s02i=a.y+c.y, d02r=a.x-c.x, d02i=a.y-c.y;
    float s13r=b.x+d.x, s13i=b.y+d.y, d13r=b.x-d.x, d13i=b.y-d.y;
    float2 E0 = make_float2(s02r+s13r, s02i+s13i);
    float2 E1 = make_float2(d02r+d13i, d02i-d13r);   // d02 - i*d13
    float2 E2 = make_float2(s02r-s13r, s02i-s13i);
    float2 E3 = make_float2(d02r-d13i, d02i+d13r);
    a=xin[1]; b=xin[3]; c=xin[5]; d=xin[7];
    s02r=a.x+c.x; s02i=a.y+c.y; d02r=a.x-c.x; d02i=a.y-c.y;
    s13r=b.x+d.x; s13i=b.y+d.y; d13r=b.x-d.x; d13i=b.y-d.y;
    float2 O0 = make_float2(s02r+s13r, s02i+s13i);
    float2 O1 = make_float2(d02r+d13i, d02i-d13r);
    float2 O2 = make_float2(s02r-s13r, s02i-s13i);
    float2 O3 = make_float2(d02r-d13i, d02i+d13r);
    float t1r = S*(O1.x + O1.y), t1i = S*(O1.y - O1.x);   // W8^1 * O1
    float t2r = O2.y,            t2i = -O2.x;             // W8^2 = -i
    float t3r = S*(O3.y - O3.x), t3i = -S*(O3.x + O3.y);  // W8^3
    Y[0] = make_float2(E0.x + O0.x, E0.y + O0.y);
    Y[4] = make_float2(E0.x - O0.x, E0.y - O0.y);
    Y[1] = make_float2(E1.x + t1r,  E1.y + t1i);
    Y[5] = make_float2(E1.x - t1r,  E1.y - t1i);
    Y[2] = make_float2(E2.x + t2r,  E2.y + t2i);
    Y[6] = make_float2(E2.x - t2r,  E2.y - t2i);
    Y[3] = make_float2(E3.x + t3r,  E3.y + t3i);
    Y[7] = make_float2(E3.x - t3r,  E3.y - t3i);
}

// one-pass bucket scatter + sum(q) + sum(q^2) into per-slot accumulators
__global__ void scatter_q_kernel(const float* __restrict__ coords,
                                 const float* __restrict__ box,
                                 const float* __restrict__ charges,
                                 int* __restrict__ counts,
                                 float4* __restrict__ sorted,
                                 double* __restrict__ qslots,
                                 double* __restrict__ q2slots, int n) {
    int i = blockIdx.x*blockDim.x + threadIdx.x;
    float v = 0.f, v2 = 0.f;
    if (i < n) {
        float p[3]; atom_pos(box, coords[3*i], coords[3*i+1], coords[3*i+2], p);
        float q = charges[i];
        v = q; v2 = q*q;
        int t[3];
        #pragma unroll
        for (int d=0; d<3; ++d) t[d] = wrap120((int)floorf(p[d])) / TILE;
        int tile = (t[0]*NTPD + t[1])*NTPD + t[2];
        int idx = atomicAdd(&counts[tile], 1);
        if (idx < CAP) sorted[tile*CAP + idx] = make_float4(p[0], p[1], p[2], q);
    }
    #pragma unroll
    for (int o=32;o>0;o>>=1) { v += __shfl_down(v,o,64); v2 += __shfl_down(v2,o,64); }
    __shared__ float s1[4], s2[4];
    int lane = threadIdx.x & 63, w = threadIdx.x >> 6;
    if (lane==0) { s1[w]=v; s2[w]=v2; }
    __syncthreads();
    if (threadIdx.x==0) {
        for (int j=1;j<4;j++) { v += s1[j]; v2 += s2[j]; }
        int slot = (blockIdx.x & (NSLOT-1)) * SLOTSTRIDE;
        atomicAdd(&qslots[slot],  (double)v);
        atomicAdd(&q2slots[slot], (double)v2);
    }
}

// Register-column spread, round-8: r7 structure + PARITY-BALANCED atom split.
// r7 post-mortem: contiguous half-split [0,64)/[64,128) with mean cnt ~100
// gave waves 64/36 atoms (1.28x critical-path imbalance) -> ate the gain.
// Fix: waves of a B-pair take even/odd j (balanced for any cnt).
// Staging: all three weight arrays stride-20 -> zeroed via 5x b128 each.
// Combine epilogue unchanged (deterministic two-pass, no atomics).
__global__ void __launch_bounds__(256, 4)
spread_tile_kernel(const float4* __restrict__ sorted,
                   const int* __restrict__ counts,
                   float* __restrict__ buf) {
    int tile = blockIdx.x;
    int tx = tile / (NTPD*NTPD);
    int rem = tile - tx*NTPD*NTPD;
    int ty = rem / NTPD;
    int tz = rem - ty*NTPD;
    int bx = tx*TILE, by = ty*TILE, bz = tz*TILE;

    __shared__ float smem[SMEMF];
    int* lys = (int*)&smem[LYS_OFF];

    int tid  = threadIdx.x;
    int wv   = tid >> 6;
    int lane = tid & 63;
    int half = wv & 1;                    // parity: waves 0,2 -> even j; 1,3 -> odd j
    int blo  = (wv < 2) ? 0 : 9;          // B-range base
    int t3   = lane / 17; if (t3 > 2) t3 = 2;
    int A    = lane - 17*t3; if (A > 16) A = 16;
    bool owner = (lane < 51);
    int B0   = blo + 3*t3;
    bool c2ok = (B0 + 2 <= 16);           // third column valid (false only B0=15)

    v2f   acc2[3][8];
    float acc16[3];
    #pragma unroll
    for (int c=0;c<3;++c) {
        #pragma unroll
        for (int k=0;k<8;++k) acc2[c][k] = (v2f){0.f,0.f};
        acc16[c] = 0.f;
    }

    int cntT = min(counts[tile], CAP);
    const float4* src = sorted + (size_t)tile*CAP;

    for (int start = 0; start < cntT; start += CHUNK) {
        int jn = cntT - start; if (jn > CHUNK) jn = CHUNK;
        __syncthreads();                 // prev-chunk readers done
        if (tid < jn) {
            float4 s = src[start + tid];
            float fx = floorf(s.x), fy = floorf(s.y), fz = floorf(s.z);
            float wx[6]; lag6(s.x - (fx + 0.5f), wx);
            float wy[6]; lag6(s.y - (fy + 0.5f), wy);
            float wz[6]; lag6(s.z - (fz + 0.5f), wz);
            int lx = wrap120((int)fx) - bx;
            int ly = wrap120((int)fy) - by;
            int lz = wrap120((int)fz) - bz;
            float4 z4 = make_float4(0.f,0.f,0.f,0.f);
            float4* px = (float4*)&smem[WXA_OFF + tid*ZPAD];
            float4* py = (float4*)&smem[WYA_OFF + tid*ZPAD];
            float4* pz = (float4*)&smem[WZA_OFF + tid*ZPAD];
            #pragma unroll
            for (int k=0;k<5;++k) { px[k]=z4; py[k]=z4; pz[k]=z4; }
            #pragma unroll
            for (int k=0;k<6;++k) {
                smem[WXA_OFF + tid*ZPAD + lx + k] = wx[k];
                smem[WYA_OFF + tid*ZPAD + ly + k] = wy[k];
                smem[WZA_OFF + tid*ZPAD + lz + k] = wz[k]*s.w;
            }
            lys[tid] = ly;
        }
        __syncthreads();
        int idxA = lane, idxB = 64 + lane;
        int lyA = lys[idxA], lyB = lys[idxB];       // stale-safe (guarded)
        bool rA = blo ? (lyA >= 4) : (lyA <= 8);
        bool rB = blo ? (lyB >= 4) : (lyB <= 8);
        bool gA = (idxA < jn) && rA && ((idxA & 1) == half);
        bool gB = (idxB < jn) && rB && ((idxB & 1) == half);
        unsigned long long mA = __ballot(gA);
        unsigned long long mB = __ballot(gB);
        auto body = [&](int j) {
            float wx_ = smem[WXA_OFF + j*ZPAD + A];
            float wy0 = smem[WYA_OFF + j*ZPAD + B0];
            float wy1 = smem[WYA_OFF + j*ZPAD + B0 + 1];
            float wy2 = smem[WYA_OFF + j*ZPAD + B0 + 2];   // in-row even if B0+2==17 (pad)
            float w2c[3];
            w2c[0] = wx_*wy0;
            w2c[1] = wx_*wy1;
            w2c[2] = c2ok ? wx_*wy2 : 0.f;
            const float4* zp = (const float4*)&smem[WZA_OFF + j*ZPAD];
            float4 z0 = zp[0], z1 = zp[1], z2 = zp[2], z3 = zp[3];
            float z16 = smem[WZA_OFF + j*ZPAD + 16];
            v2f zz[8];
            zz[0]=(v2f){z0.x,z0.y}; zz[1]=(v2f){z0.z,z0.w};
            zz[2]=(v2f){z1.x,z1.y}; zz[3]=(v2f){z1.z,z1.w};
            zz[4]=(v2f){z2.x,z2.y}; zz[5]=(v2f){z2.z,z2.w};
            zz[6]=(v2f){z3.x,z3.y}; zz[7]=(v2f){z3.z,z3.w};
            #pragma unroll
            for (int c=0;c<3;++c) {
                v2f wv2 = (v2f){w2c[c], w2c[c]};
                #pragma unroll
                for (int k=0;k<8;++k) acc2[c][k] += wv2 * zz[k];
                acc16[c] = fmaf(w2c[c], z16, acc16[c]);
            }
        };
        while (mA) { int j = __builtin_ctzll(mA); mA &= mA - 1ull; body(j); }
        while (mB) { int j = 64 + __builtin_ctzll(mB); mB &= mB - 1ull; body(j); }
    }
    __syncthreads();
    // overlay combine: waves 0,2 write their parity-partials (disjoint B-sets),
    // then waves 1,3 add theirs (exclusive per-cell, deterministic).
    if ((half == 0) && owner) {
        #pragma unroll
        for (int c=0;c<3;++c) {
            int Bc = B0 + c;
            if (Bc <= 16) {
                float* dst = &smem[(A*17 + Bc)*ZPAD];
                *(float4*)&dst[0]  = make_float4(acc2[c][0].x, acc2[c][0].y, acc2[c][1].x, acc2[c][1].y);
                *(float4*)&dst[4]  = make_float4(acc2[c][2].x, acc2[c][2].y, acc2[c][3].x, acc2[c][3].y);
                *(float4*)&dst[8]  = make_float4(acc2[c][4].x, acc2[c][4].y, acc2[c][5].x, acc2[c][5].y);
                *(float4*)&dst[12] = make_float4(acc2[c][6].x, acc2[c][6].y, acc2[c][7].x, acc2[c][7].y);
                dst[16] = acc16[c];
            }
        }
    }
    __syncthreads();
    if ((half == 1) && owner) {
        #pragma unroll
        for (int c=0;c<3;++c) {
            int Bc = B0 + c;
            if (Bc <= 16) {
                float* dst = &smem[(A*17 + Bc)*ZPAD];
                float4 a0 = *(float4*)&dst[0],  a1 = *(float4*)&dst[4];
                float4 a2 = *(float4*)&dst[8],  a3 = *(float4*)&dst[12];
                float  a4 = dst[16];
                *(float4*)&dst[0]  = make_float4(a0.x+acc2[c][0].x, a0.y+acc2[c][0].y, a0.z+acc2[c][1].x, a0.w+acc2[c][1].y);
                *(float4*)&dst[4]  = make_float4(a1.x+acc2[c][2].x, a1.y+acc2[c][2].y, a1.z+acc2[c][3].x, a1.w+acc2[c][3].y);
                *(float4*)&dst[8]  = make_float4(a2.x+acc2[c][4].x, a2.y+acc2[c][4].y, a2.z+acc2[c][5].x, a2.w+acc2[c][5].y);
                *(float4*)&dst[12] = make_float4(a3.x+acc2[c][6].x, a3.y+acc2[c][6].y, a3.z+acc2[c][7].x, a3.w+acc2[c][7].y);
                dst[16] = a4 + acc16[c];
            }
        }
    }
    __syncthreads();
    float4* bp = (float4*)(buf + (size_t)tile * FPSTRIDE);
    const float4* sp = (const float4*)smem;
    for (int i = tid; i < FPSTRIDE/4; i += 256) bp[i] = sp[i];
}

// ---- radix-8 decimated 120-point DFT inner loop ----
// X[k] = sum_{j<15} Y[k&7][j] * W120^{k*j};  3 strands (j mod 3) for ILP.
// w1 twiddle from per-block LDS table (one sincos per k per block, not per output).
#define DFT15_BODY(Yp, kfreq, RE, IM)                                        \
    float w1r = tw[kfreq].x, w1i = tw[kfreq].y;                              \
    float w2r = w1r*w1r - w1i*w1i, w2i = 2.f*w1r*w1i;                        \
    float w3r = w2r*w1r - w2i*w1i, w3i = w2r*w1i + w2i*w1r;                  \
    float ar=1.f, ai=0.f, br=w1r, bi=w1i, cr=w2r, ci=w2i;                    \
    float r0_=0.f,i0_=0.f,r1_=0.f,i1_=0.f,r2_=0.f,i2_=0.f;                   \
    _Pragma("unroll")                                                        \
    for (int s_=0;s_<5;++s_) {                                               \
        float2 ya = (Yp)[3*s_], yb = (Yp)[3*s_+1], yc = (Yp)[3*s_+2];        \
        r0_ = fmaf(ya.x, ar, fmaf(-ya.y, ai, r0_));                          \
        i0_ = fmaf(ya.x, ai, fmaf( ya.y, ar, i0_));                          \
        r1_ = fmaf(yb.x, br, fmaf(-yb.y, bi, r1_));                          \
        i1_ = fmaf(yb.x, bi, fmaf( yb.y, br, i1_));                          \
        r2_ = fmaf(yc.x, cr, fmaf(-yc.y, ci, r2_));                          \
        i2_ = fmaf(yc.x, ci, fmaf( yc.y, cr, i2_));                          \
        float n_;                                                            \
        n_ = ar*w3r - ai*w3i; ai = ar*w3i + ai*w3r; ar = n_;                 \
        n_ = br*w3r - bi*w3i; bi = br*w3i + bi*w3r; br = n_;                 \
        n_ = cr*w3r - ci*w3i; ci = cr*w3i + ci*w3r; cr = n_;                 \
    }                                                                        \
    float RE = (r0_+r1_)+r2_, IM = (i0_+i1_)+i2_;

#define TWIDDLE_INIT()                                                       \
    __shared__ float2 tw[120];                                               \
    for (int k_ = threadIdx.x; k_ < 120; k_ += blockDim.x) {                 \
        float s_, c_; __sincosf(W120C * (float)k_, &s_, &c_);                \
        tw[k_] = make_float2(c_, s_);                                        \
    }

// stage 1: halo-gather + rfft along z (radix-8 pre-combine). out C1[x][kz][y].
__global__ void __launch_bounds__(256)
fft_z_kernel(const float* __restrict__ buf,
             float2* __restrict__ C1) {
    int x  = blockIdx.x / 10;
    int y0 = (blockIdx.x - x*10) * YCH;
    __shared__ float  lin[YCH][121];
    __shared__ float2 Ys[YCH][YROW];    // per line: 8 rows * 17 (+1 pad)
    TWIDDLE_INIT()

    int txA[2], lxA[2];
    int nx = halo_pairs(x, txA, lxA);

    for (int i = threadIdx.x; i < YCH*120; i += 256) {
        int yl = i / 120, z = i - yl*120;
        int tyA[2], lyA[2]; int ny = halo_pairs(y0 + yl, tyA, lyA);
        int tzA[2], lzA[2]; int nz = halo_pairs(z, tzA, lzA);
        float s = 0.f;
        for (int ii=0; ii<nx; ++ii)
            for (int jj=0; jj<ny; ++jj)
                for (int kk=0; kk<nz; ++kk) {
                    int tile = (txA[ii]*NTPD + tyA[jj])*NTPD + tzA[kk];
                    int cell = (lxA[ii]*FP + lyA[jj])*ZPAD + lzA[kk];
                    s += buf[(size_t)tile*FPSTRIDE + cell];
                }
        lin[yl][z] = s;
    }
    __syncthreads();
    // radix-8 combine: z = 15m + j ; Y[r][j] = sum_m x W8^{rm}
    for (int t = threadIdx.x; t < YCH*15; t += 256) {
        int yl = t / 15, j = t - (t/15)*15;
        float2 xin[8], Yo[8];
        #pragma unroll
        for (int m=0;m<8;++m) xin[m] = make_float2(lin[yl][15*m+j], 0.f);
        dft8(xin, Yo);
        #pragma unroll
        for (int r=0;r<8;++r) Ys[yl][r*17+j] = Yo[r];
    }
    __syncthreads();
    for (int o = threadIdx.x; o < YCH*NKZ; o += 256) {
        int kz = o / YCH, yl = o - (o/YCH)*YCH;
        const float2* Yp = &Ys[yl][(kz&7)*17];
        DFT15_BODY(Yp, kz, re, im)
        C1[(x*NKZ + kz)*120 + y0 + yl] = make_float2(re, im);
    }
}

// stage 2: cfft along y (radix-8). block = (4 consecutive x, kz). out C2[kz][ky][x].
__global__ void __launch_bounds__(256)
fft_y_kernel(const float2* __restrict__ C1,
             float2* __restrict__ C2) {
    int xc = blockIdx.x / NKZ;
    int kz = blockIdx.x - xc*NKZ;
    int x0 = xc * XCH;
    __shared__ float2 lin[XCH][121];
    __shared__ float2 Ys[XCH][YROW];
    TWIDDLE_INIT()
    for (int i = threadIdx.x; i < XCH*120; i += 256) {
        int xo = i / 120, y = i - (i/120)*120;
        lin[xo][y] = C1[((x0+xo)*NKZ + kz)*120 + y];
    }
    __syncthreads();
    for (int t = threadIdx.x; t < XCH*15; t += 256) {
        int xo = t / 15, j = t - (t/15)*15;
        float2 xin[8], Yo[8];
        #pragma unroll
        for (int m=0;m<8;++m) xin[m] = lin[xo][15*m+j];
        dft8(xin, Yo);
        #pragma unroll
        for (int r=0;r<8;++r) Ys[xo][r*17+j] = Yo[r];
    }
    __syncthreads();
    for (int o = threadIdx.x; o < XCH*120; o += 256) {
        int ky = o >> 2, xo = o & 3;
        const float2* Yp = &Ys[xo][(ky&7)*17];
        DFT15_BODY(Yp, ky, re, im)
        C2[(kz*120 + ky)*120 + x0 + xo] = make_float2(re, im);
    }
}

// stage 3: cfft along x (radix-8) + G-weighted energy (slotted atomic).
__global__ void __launch_bounds__(256)
fft_x_energy_kernel(const float2* __restrict__ C2,
                    const float* __restrict__ box,
                    double* __restrict__ ekslots) {
    int kyc = blockIdx.x / NKZ;
    int kz  = blockIdx.x - kyc*NKZ;
    int ky0 = kyc * XCH;
    __shared__ float2 lin[XCH][121];
    __shared__ float2 Ys[XCH][YROW];
    TWIDDLE_INIT()
    const float2* src = C2 + (kz*120 + ky0)*120;
    for (int i = threadIdx.x; i < XCH*120; i += 256) {
        int kyo = i / 120, xx = i - (i/120)*120;
        lin[kyo][xx] = src[i];
    }
    __syncthreads();
    for (int t = threadIdx.x; t < XCH*15; t += 256) {
        int kyo = t / 15, j = t - (t/15)*15;
        float2 xin[8], Yo[8];
        #pragma unroll
        for (int m=0;m<8;++m) xin[m] = lin[kyo][15*m+j];
        dft8(xin, Yo);
        #pragma unroll
        for (int r=0;r<8;++r) Ys[kyo][r*17+j] = Yo[r];
    }
    __syncthreads();
    float ib[9]; inv3(box, ib);
    const float TWOPI = 6.283185307179586f;
    float wzf = (kz==0 || kz==60) ? 1.0f : 2.0f;
    float contrib = 0.f;
    for (int o = threadIdx.x; o < XCH*120; o += 256) {
        int kyo = o / 120, kx = o - (o/120)*120;
        int ky = ky0 + kyo;
        const float2* Yp = &Ys[kyo][(kx&7)*17];
        DFT15_BODY(Yp, kx, re, im)
        if (!(kx==0 && ky==0 && kz==0)) {
            float mx = (kx < 60) ? (float)kx : (float)(kx - 120);
            float my = (ky < 60) ? (float)ky : (float)(ky - 120);
            float mz = (float)kz;
            float k0 = TWOPI*(mx*ib[0] + my*ib[1] + mz*ib[2]);
            float k1 = TWOPI*(mx*ib[3] + my*ib[4] + mz*ib[5]);
            float k2 = TWOPI*(mx*ib[6] + my*ib[7] + mz*ib[8]);
            float ksq = k0*k0 + k1*k1 + k2*k2;
            float G = 12.566370614359172f * __expf(-0.5f*(float)(ALPHA_C*ALPHA_C)*ksq) / ksq;
            contrib += wzf * G * (re*re + im*im);
        }
    }
    #pragma unroll
    for (int o=32;o>0;o>>=1) contrib += __shfl_down(contrib,o,64);
    __shared__ float sm[4];
    int lane = threadIdx.x & 63, w = threadIdx.x >> 6;
    if (lane==0) sm[w] = contrib;
    __syncthreads();
    if (threadIdx.x==0)
        atomicAdd(&ekslots[(blockIdx.x & (NSLOT-1)) * SLOTSTRIDE],
                  (double)(sm[0]+sm[1]+sm[2]+sm[3]));
}

// 64-lane slot reduction + closed-form corrections
__global__ void finalize_kernel(const double* __restrict__ ekslots,
                                const double* __restrict__ qslots,
                                const double* __restrict__ q2slots,
                                const float* __restrict__ box,
                                float* __restrict__ out) {
    int lane = threadIdx.x;
    double ek  = ekslots[lane*SLOTSTRIDE];
    double sq  = qslots [lane*SLOTSTRIDE];
    double sq2 = q2slots[lane*SLOTSTRIDE];
    #pragma unroll
    for (int o=32;o>0;o>>=1) {
        ek  += __shfl_down(ek,  o, 64);
        sq  += __shfl_down(sq,  o, 64);
        sq2 += __shfl_down(sq2, o, 64);
    }
    if (lane == 0) {
        double a00=box[0],a01=box[1],a02=box[2],a10=box[3],a11=box[4],a12=box[5],a20=box[6],a21=box[7],a22=box[8];
        double det = a00*(a11*a22-a12*a21) - a01*(a10*a22-a12*a20) + a02*(a10*a21-a11*a20);
        double vol = fabs(det);
        double E = ek/(2.0*vol)
                 - 0.5*sqrt(2.0/M_PI)/ALPHA_C * sq2
                 - M_PI*ALPHA_C*ALPHA_C * sq*sq / vol;
        out[0] = (float)E;
    }
}

extern "C" void kernel_launch(void* const* d_in, const int* in_sizes, int n_in,
                              void* d_out, int out_size, void* d_ws, size_t ws_size,
                              hipStream_t stream) {
    const float* coords  = (const float*)d_in[0];
    const float* box     = (const float*)d_in[1];
    const float* charges = (const float*)d_in[2];
    int n = in_sizes[0] / 3;

    char* ws = (char*)d_ws;
    double* ekslots = (double*)(ws + EK_OFF);
    double* qslots  = (double*)(ws + Q_OFF);
    double* q2slots = (double*)(ws + Q2_OFF);
    float*  buf     = (float*) (ws + BUF_OFF);
    float2* C1      = (float2*)(ws + C1_OFF);
    float2* C2      = (float2*)(ws + C2_OFF);
    int* counts     = (int*)(ws + COUNTS_OFF);
    float4* sorted  = (float4*)(ws + SORTED_OFF);

    int gA = (n + 255)/256;
    // one memset covers slots [0,12288) + counts [12288,16384)
    hipMemsetAsync(ws, 0, 16384, stream);
    scatter_q_kernel<<<gA, 256, 0, stream>>>(coords, box, charges, counts, sorted, qslots, q2slots, n);
    spread_tile_kernel<<<NTILE, 256, 0, stream>>>(sorted, counts, buf);
    fft_z_kernel<<<120*10, 256, 0, stream>>>(buf, C1);
    fft_y_kernel<<<30*NKZ, 256, 0, stream>>>(C1, C2);
    fft_x_energy_kernel<<<NKZ*30, 256, 0, stream>>>(C2, box, ekslots);
    finalize_kernel<<<1, 64, 0, stream>>>(ekslots, qslots, q2slots, box, (float*)d_out);
}